// Round 11
// baseline (140.109 us; speedup 1.0000x reference)
//
#include <hip/hip_runtime.h>
#include <hip/hip_bf16.h>

typedef unsigned short u16;
typedef __attribute__((ext_vector_type(8))) __bf16 bf16x8;
typedef __attribute__((ext_vector_type(4))) float f32x4;

#define S_LEN 2048
#define DMODEL 1024
#define NHEAD 16
#define HSZ 64

__device__ __forceinline__ u16 f2bf(float f) {
  union { __hip_bfloat16 b; u16 u; } c;
  c.b = __float2bfloat16(f);
  return c.u;
}

__device__ __forceinline__ float bf2f(u16 u) {
  union { unsigned int i; float f; } c;
  c.i = ((unsigned int)u) << 16;
  return c.f;
}

// raw v_exp_f32 (D = 2^S0) -- 1 inst vs ~5 for libm exp2f
__device__ __forceinline__ float fexp2(float x) {
#if __has_builtin(__builtin_amdgcn_exp2f)
  return __builtin_amdgcn_exp2f(x);
#else
  return exp2f(x);
#endif
}

// v_cvt_pk_bf16_f32: pack 2 f32 -> 2 bf16 (RNE), 1 inst vs ~12 for 2x f2bf
__device__ __forceinline__ unsigned int cvtpk(float lo, float hi) {
  unsigned int r;
  asm("v_cvt_pk_bf16_f32 %0, %1, %2" : "=v"(r) : "v"(lo), "v"(hi));
  return r;
}

__device__ __forceinline__ void gload_lds16(const void* g, void* l) {
  __builtin_amdgcn_global_load_lds(
      (const __attribute__((address_space(1))) void*)g,
      (__attribute__((address_space(3))) void*)l, 16, 0, 0);
}

__device__ __forceinline__ f32x4 mfma16(bf16x8 a, bf16x8 b, f32x4 c) {
  return __builtin_amdgcn_mfma_f32_16x16x32_bf16(a, b, c, 0, 0, 0);
}

// ---------------- fp32 -> bf16 convert (vectorized) ----------------
__global__ __launch_bounds__(256) void convert_f2b_kernel(const float* __restrict__ in,
                                                          u16* __restrict__ out) {
  int i = (blockIdx.x * 256 + threadIdx.x) * 4;
  float4 v = *(const float4*)(in + i);
  ushort4 o;
  o.x = f2bf(v.x); o.y = f2bf(v.y); o.z = f2bf(v.z); o.w = f2bf(v.w);
  *(ushort4*)(out + i) = o;
}

// ------------- W [K][N] fp32 -> W^T [N][K] bf16 (LDS tiled) -------------
__global__ __launch_bounds__(256) void transpose_w_kernel(
    const float* __restrict__ W0, const float* __restrict__ W1,
    const float* __restrict__ W2, const float* __restrict__ W3,
    u16* __restrict__ T0, u16* __restrict__ T1,
    u16* __restrict__ T2, u16* __restrict__ T3) {
  int z = blockIdx.z;
  const float* W = (z == 0) ? W0 : ((z == 1) ? W1 : ((z == 2) ? W2 : W3));
  u16* T = (z == 0) ? T0 : ((z == 1) ? T1 : ((z == 2) ? T2 : T3));
  __shared__ float tile[64][65];
  int t = threadIdx.x;
  int k0 = blockIdx.y * 64, n0 = blockIdx.x * 64;
#pragma unroll
  for (int j = 0; j < 4; ++j) {
    int idx = j * 256 + t;
    int row = idx >> 4, c4 = idx & 15;
    float4 v = *(const float4*)(W + (size_t)(k0 + row) * DMODEL + n0 + c4 * 4);
    tile[row][c4 * 4 + 0] = v.x; tile[row][c4 * 4 + 1] = v.y;
    tile[row][c4 * 4 + 2] = v.z; tile[row][c4 * 4 + 3] = v.w;
  }
  __syncthreads();
#pragma unroll
  for (int j = 0; j < 4; ++j) {
    int idx = j * 256 + t;
    int orow = idx >> 4, c4 = idx & 15;
    ushort4 o;
    o.x = f2bf(tile[c4 * 4 + 0][orow]);
    o.y = f2bf(tile[c4 * 4 + 1][orow]);
    o.z = f2bf(tile[c4 * 4 + 2][orow]);
    o.w = f2bf(tile[c4 * 4 + 3][orow]);
    *(ushort4*)(T + (size_t)(n0 + orow) * DMODEL + k0 + c4 * 4) = o;
  }
}

// ------------- Vh [bh][S][64] -> Vt [bh][64][S] bf16 -------------
__global__ __launch_bounds__(256) void transpose_v_kernel(const u16* __restrict__ Vh,
                                                          u16* __restrict__ Vt) {
  int bh = blockIdx.y;
  int s0 = blockIdx.x * 64;
  __shared__ __align__(16) u16 tile[64][72];
  int t = threadIdx.x;
#pragma unroll
  for (int j = 0; j < 4; ++j) {
    int idx = j * 256 + t;
    int row = idx >> 4, c4 = idx & 15;
    *(ushort4*)&tile[row][c4 * 4] =
        *(const ushort4*)(Vh + ((size_t)bh * S_LEN + s0 + row) * HSZ + c4 * 4);
  }
  __syncthreads();
#pragma unroll
  for (int j = 0; j < 4; ++j) {
    int idx = j * 256 + t;
    int orow = idx >> 4, c4 = idx & 15;
    ushort4 o;
    o.x = tile[c4 * 4 + 0][orow];
    o.y = tile[c4 * 4 + 1][orow];
    o.z = tile[c4 * 4 + 2][orow];
    o.w = tile[c4 * 4 + 3][orow];
    *(ushort4*)(Vt + ((size_t)bh * HSZ + orow) * S_LEN + s0 + c4 * 4) = o;
  }
}

// ------------- GEMM core, templated on m-frags/wave (WM*32 = tile rows) -------------
template <int WM>
__device__ __forceinline__ void gemm_core(const u16* __restrict__ A,
                                          const u16* __restrict__ Bt,
                                          u16* ldsbuf, f32x4 (&acc)[WM][4],
                                          int m0, int n0) {
  const int t = threadIdx.x;
  const int wave = t >> 6, lane = t & 63;
  const int l15 = lane & 15, l4 = lane >> 4;
  const int wr = wave >> 1, wc = wave & 1;
  u16* Asm = ldsbuf;                 // [WM*32][32]
  u16* Bsm = ldsbuf + WM * 1024;     // [128][32]
  for (int kt = 0; kt < DMODEL / 32; ++kt) {
    int kb = kt * 32;
#pragma unroll
    for (int j = 0; j < WM / 2; ++j) {
      int ci = j * 256 + t;
      int row = ci >> 2, kc = ci & 3;
      gload_lds16(A + (size_t)(m0 + row) * DMODEL + kb + kc * 8,
                  Asm + (j * 256 + wave * 64) * 8);
    }
#pragma unroll
    for (int j = 0; j < 2; ++j) {
      int ci = j * 256 + t;
      int row = ci >> 2, kc = ci & 3;
      gload_lds16(Bt + (size_t)(n0 + row) * DMODEL + kb + kc * 8,
                  Bsm + (j * 256 + wave * 64) * 8);
    }
    __syncthreads();
    bf16x8 af[WM], bfr[4];
#pragma unroll
    for (int m = 0; m < WM; ++m)
      af[m] = *(const bf16x8*)(Asm + ((wr * (WM * 16) + m * 16 + l15) * 32 + l4 * 8));
#pragma unroll
    for (int n = 0; n < 4; ++n)
      bfr[n] = *(const bf16x8*)(Bsm + ((wc * 64 + n * 16 + l15) * 32 + l4 * 8));
#pragma unroll
    for (int m = 0; m < WM; ++m)
#pragma unroll
      for (int n = 0; n < 4; ++n)
        acc[m][n] = mfma16(af[m], bfr[n], acc[m][n]);
    __syncthreads();
  }
}

// ------------- QKV projection; Q pre-scaled by 0.125*log2(e) (exp2 domain) -------------
__global__ __launch_bounds__(256) void gemm_qkv_kernel(
    const u16* __restrict__ A, const u16* __restrict__ B0, const u16* __restrict__ B1,
    const u16* __restrict__ B2, const float* __restrict__ bias0,
    const float* __restrict__ bias1, const float* __restrict__ bias2,
    u16* __restrict__ d0, u16* __restrict__ d1, u16* __restrict__ d2) {
  __shared__ __align__(16) u16 lds[8192];
  int z = blockIdx.z;
  const u16* Bt = (z == 0) ? B0 : ((z == 1) ? B1 : B2);
  const float* bias = (z == 0) ? bias0 : ((z == 1) ? bias1 : bias2);
  u16* dst = (z == 0) ? d0 : ((z == 1) ? d1 : d2);
  const float sc = (z == 0) ? 0.18033688011112042f : 1.0f;  // 0.125*log2e
  int m0 = blockIdx.y * 128, n0 = blockIdx.x * 128;
  f32x4 acc[4][4] = {};
  gemm_core<4>(A, Bt, lds, acc, m0, n0);
  const int t = threadIdx.x;
  const int wave = t >> 6, lane = t & 63, l15 = lane & 15, l4 = lane >> 4;
  const int wr = wave >> 1, wc = wave & 1;
#pragma unroll
  for (int n = 0; n < 4; ++n) {
    int colg = n0 + wc * 64 + n * 16 + l15;
    float bn = bias[colg];
    int h = colg >> 6, hs = colg & 63;
#pragma unroll
    for (int m = 0; m < 4; ++m) {
#pragma unroll
      for (int i = 0; i < 4; ++i) {
        int rowg = m0 + wr * 64 + m * 16 + 4 * l4 + i;
        int b = rowg >> 11, s = rowg & 2047;
        dst[(size_t)(b * NHEAD + h) * S_LEN * HSZ + (size_t)s * HSZ + hs] =
            f2bf((acc[m][n][i] + bn) * sc);
      }
    }
  }
}

// ------------- output projection: 64x128 tile, fp32 out -------------
__global__ __launch_bounds__(256) void gemm_out_kernel(const u16* __restrict__ A,
                                                       const u16* __restrict__ Bt,
                                                       const float* __restrict__ bias,
                                                       float* __restrict__ out) {
  __shared__ __align__(16) u16 lds[6144];
  int m0 = blockIdx.y * 64, n0 = blockIdx.x * 128;
  f32x4 acc[2][4] = {};
  gemm_core<2>(A, Bt, lds, acc, m0, n0);
  const int t = threadIdx.x;
  const int wave = t >> 6, lane = t & 63, l15 = lane & 15, l4 = lane >> 4;
  const int wr = wave >> 1, wc = wave & 1;
#pragma unroll
  for (int n = 0; n < 4; ++n) {
    int colg = n0 + wc * 64 + n * 16 + l15;
    float bn = bias[colg];
#pragma unroll
    for (int m = 0; m < 2; ++m) {
#pragma unroll
      for (int i = 0; i < 4; ++i) {
        int rowg = m0 + wr * 32 + m * 16 + 4 * l4 + i;
        out[(size_t)rowg * DMODEL + colg] = acc[m][n][i] + bn;
      }
    }
  }
}

// ------------- flash attention (causal), split-KV, KVB=128 -------------
// R10 structure with KV tile width doubled 64 -> 128: tile-iterations drop
// 33792 -> 17408, halving the per-tile fixed serial cost (16 shfl chains,
// corr/lrun update, oacc rescale, K-load wait) that six scheduling rounds
// could not dent. Per-element work (exp, MFMA, P pack) is count-neutral.
// Block = one 32-row q-tile of one bh; wave w handles kv tiles {w, w+4, ...}.
// Private (m,l,O) per wave; one barrier; LDS merge with exp2 rescale.
__global__ __launch_bounds__(256, 2) void attn_kernel(const u16* __restrict__ Qh,
                                                      const u16* __restrict__ Kh,
                                                      const u16* __restrict__ Vt,
                                                      u16* __restrict__ Ob) {
  __shared__ __align__(16) u16 Pl[4][32][136];  // [q][kv=128]+pad; Opart alias
  __shared__ float Ml[4][32];
  __shared__ float Ll[4][32];
  const int tixd = threadIdx.x;
  const int wave = tixd >> 6, lane = tixd & 63;
  const int l15 = lane & 15, l4 = lane >> 4;
  const int id = blockIdx.x;
  const int bh = (id & 7) * 4 + ((id >> 3) & 3);  // XCD-local heads
  const int tt = 63 - (id >> 5);                  // longest-first
  const int q0 = tt * 32;
  const int ntile = (tt + 4) >> 2;                // kv tiles of 128 needed
  const u16* Qb = Qh + (size_t)bh * S_LEN * HSZ;
  const u16* Kb = Kh + (size_t)bh * S_LEN * HSZ;
  const u16* Vb = Vt + (size_t)bh * HSZ * S_LEN;
  const int shbase = l4 * 20;  // lane with l15' = 4*l4+i, same l4
  u16 (*P)[136] = Pl[wave];

  bf16x8 qf[2][2];
#pragma unroll
  for (int m = 0; m < 2; ++m)
#pragma unroll
    for (int kc = 0; kc < 2; ++kc)
      qf[m][kc] = *(const bf16x8*)(Qb + (size_t)(q0 + m * 16 + l15) * HSZ + kc * 32 + l4 * 8);

  f32x4 oacc[2][4] = {};
  float mrun[2] = {-1e30f, -1e30f};
  float lrun[2] = {0.f, 0.f};

  const int nt = (ntile > wave) ? ((ntile - wave + 3) >> 2) : 0;
  for (int j = 0; j < nt; ++j) {
    const int kv0 = (wave + 4 * j) * 128;
    // K fragments for the full 128-kv tile
    bf16x8 kA[8][2];
#pragma unroll
    for (int n = 0; n < 8; ++n)
#pragma unroll
      for (int kc = 0; kc < 2; ++kc)
        kA[n][kc] = *(const bf16x8*)(Kb + (size_t)(kv0 + n * 16 + l15) * HSZ + kc * 32 + l4 * 8);

    f32x4 sacc[2][8] = {};
#pragma unroll
    for (int m = 0; m < 2; ++m)
#pragma unroll
      for (int n = 0; n < 8; ++n) {
        sacc[m][n] = mfma16(kA[n][0], qf[m][0], sacc[m][n]);
        sacc[m][n] = mfma16(kA[n][1], qf[m][1], sacc[m][n]);
      }

    // first V half (kv 0..63 of tile): latency hides under mask+softmax
    bf16x8 vfA[2][4];
#pragma unroll
    for (int kb = 0; kb < 2; ++kb)
#pragma unroll
      for (int n = 0; n < 4; ++n)
        vfA[kb][n] = *(const bf16x8*)(Vb + (size_t)(n * 16 + l15) * S_LEN + kv0 + kb * 32 + l4 * 8);

    if (kv0 + 127 > q0) {
#pragma unroll
      for (int m = 0; m < 2; ++m)
#pragma unroll
        for (int n = 0; n < 8; ++n)
#pragma unroll
          for (int i = 0; i < 4; ++i)
            if (kv0 + n * 16 + 4 * l4 + i > q0 + m * 16 + l15) sacc[m][n][i] = -1e30f;
    }

#pragma unroll
    for (int m = 0; m < 2; ++m) {
      // max3-fusable tree over the 32 in-lane values
      float a0 = fmaxf(fmaxf(sacc[m][0][0], sacc[m][0][1]),
                       fmaxf(sacc[m][0][2], sacc[m][0][3]));
      float a1 = fmaxf(fmaxf(sacc[m][1][0], sacc[m][1][1]),
                       fmaxf(sacc[m][1][2], sacc[m][1][3]));
      float a2 = fmaxf(fmaxf(sacc[m][2][0], sacc[m][2][1]),
                       fmaxf(sacc[m][2][2], sacc[m][2][3]));
      float a3 = fmaxf(fmaxf(sacc[m][3][0], sacc[m][3][1]),
                       fmaxf(sacc[m][3][2], sacc[m][3][3]));
      float a4 = fmaxf(fmaxf(sacc[m][4][0], sacc[m][4][1]),
                       fmaxf(sacc[m][4][2], sacc[m][4][3]));
      float a5 = fmaxf(fmaxf(sacc[m][5][0], sacc[m][5][1]),
                       fmaxf(sacc[m][5][2], sacc[m][5][3]));
      float a6 = fmaxf(fmaxf(sacc[m][6][0], sacc[m][6][1]),
                       fmaxf(sacc[m][6][2], sacc[m][6][3]));
      float a7 = fmaxf(fmaxf(sacc[m][7][0], sacc[m][7][1]),
                       fmaxf(sacc[m][7][2], sacc[m][7][3]));
      float tm = fmaxf(fmaxf(fmaxf(a0, a1), fmaxf(a2, a3)),
                       fmaxf(fmaxf(a4, a5), fmaxf(a6, a7)));
      tm = fmaxf(tm, __shfl_xor(tm, 16));
      tm = fmaxf(tm, __shfl_xor(tm, 32));
      float mnew = fmaxf(mrun[m], tm);
      float corr = fexp2(mrun[m] - mnew);
      mrun[m] = mnew;
      float rs = 0.f;
#pragma unroll
      for (int n = 0; n < 8; ++n)
#pragma unroll
        for (int i = 0; i < 4; ++i) {
          float p = fexp2(sacc[m][n][i] - mnew);
          sacc[m][n][i] = p;
          rs += p;
        }
      rs += __shfl_xor(rs, 16);
      rs += __shfl_xor(rs, 32);
      lrun[m] = lrun[m] * corr + rs;
      float c0 = __shfl(corr, shbase + 0);
      float c1 = __shfl(corr, shbase + 1);
      float c2 = __shfl(corr, shbase + 2);
      float c3 = __shfl(corr, shbase + 3);
#pragma unroll
      for (int n = 0; n < 4; ++n) {
        oacc[m][n][0] *= c0; oacc[m][n][1] *= c1;
        oacc[m][n][2] *= c2; oacc[m][n][3] *= c3;
      }
      // P pack: v_cvt_pk_bf16_f32 + b64 stores
#pragma unroll
      for (int n = 0; n < 8; ++n) {
        uint2 pk;
        pk.x = cvtpk(sacc[m][n][0], sacc[m][n][1]);
        pk.y = cvtpk(sacc[m][n][2], sacc[m][n][3]);
        *(uint2*)&P[m * 16 + l15][n * 16 + 4 * l4] = pk;
      }
    }

    // second V half (kv 64..127): latency hides under P roundtrip + PV A
    bf16x8 vfB[2][4];
#pragma unroll
    for (int kb = 0; kb < 2; ++kb)
#pragma unroll
      for (int n = 0; n < 4; ++n)
        vfB[kb][n] = *(const bf16x8*)(Vb + (size_t)(n * 16 + l15) * S_LEN + kv0 + 64 + kb * 32 + l4 * 8);

#pragma unroll
    for (int kb = 0; kb < 2; ++kb) {
      bf16x8 pf0 = *(const bf16x8*)&P[l15][kb * 32 + l4 * 8];
      bf16x8 pf1 = *(const bf16x8*)&P[16 + l15][kb * 32 + l4 * 8];
#pragma unroll
      for (int n = 0; n < 4; ++n) {
        oacc[0][n] = mfma16(pf0, vfA[kb][n], oacc[0][n]);
        oacc[1][n] = mfma16(pf1, vfA[kb][n], oacc[1][n]);
      }
    }
#pragma unroll
    for (int kb = 0; kb < 2; ++kb) {
      bf16x8 pf0 = *(const bf16x8*)&P[l15][64 + kb * 32 + l4 * 8];
      bf16x8 pf1 = *(const bf16x8*)&P[16 + l15][64 + kb * 32 + l4 * 8];
#pragma unroll
      for (int n = 0; n < 4; ++n) {
        oacc[0][n] = mfma16(pf0, vfB[kb][n], oacc[0][n]);
        oacc[1][n] = mfma16(pf1, vfB[kb][n], oacc[1][n]);
      }
    }
  }

  // publish partials; Opart aliases Pl (P dead now for this wave)
  if (l4 == 0) {
#pragma unroll
    for (int m = 0; m < 2; ++m) {
      Ml[wave][m * 16 + l15] = mrun[m];
      Ll[wave][m * 16 + l15] = lrun[m];
    }
  }
#pragma unroll
  for (int m = 0; m < 2; ++m)
#pragma unroll
    for (int n = 0; n < 4; ++n)
#pragma unroll
      for (int i = 0; i < 4; ++i)
        Pl[wave][m * 16 + 4 * l4 + i][n * 16 + l15] = f2bf(oacc[m][n][i]);
  __syncthreads();

  // merge: thread t -> row r = t>>3, col chunk c0 = (t&7)*8 (exp2 domain)
  {
    const int r = tixd >> 3;
    const int c0 = (tixd & 7) * 8;
    float m0v = Ml[0][r], m1v = Ml[1][r], m2v = Ml[2][r], m3v = Ml[3][r];
    float M = fmaxf(fmaxf(m0v, m1v), fmaxf(m2v, m3v));
    float e0 = fexp2(m0v - M), e1 = fexp2(m1v - M);
    float e2 = fexp2(m2v - M), e3 = fexp2(m3v - M);
    float L = Ll[0][r] * e0 + Ll[1][r] * e1 + Ll[2][r] * e2 + Ll[3][r] * e3;
    float invL = 1.0f / L;
    bf16x8 o0 = *(const bf16x8*)&Pl[0][r][c0];
    bf16x8 o1 = *(const bf16x8*)&Pl[1][r][c0];
    bf16x8 o2 = *(const bf16x8*)&Pl[2][r][c0];
    bf16x8 o3 = *(const bf16x8*)&Pl[3][r][c0];
    const int b = bh >> 4, h = bh & 15;
    const int srow = q0 + r;
    u16* dst = Ob + ((size_t)b * S_LEN + srow) * DMODEL + h * HSZ + c0;
    ushort4 w0, w1;
    u16* wp[2] = {(u16*)&w0, (u16*)&w1};
#pragma unroll
    for (int j2 = 0; j2 < 8; ++j2) {
      float acc = bf2f(((u16*)&o0)[j2]) * e0;
      acc += bf2f(((u16*)&o1)[j2]) * e1;
      acc += bf2f(((u16*)&o2)[j2]) * e2;
      acc += bf2f(((u16*)&o3)[j2]) * e3;
      wp[j2 >> 2][j2 & 3] = f2bf(acc * invL);
    }
    *(ushort4*)(dst + 0) = w0;
    *(ushort4*)(dst + 4) = w1;
  }
}

extern "C" void kernel_launch(void* const* d_in, const int* in_sizes, int n_in,
                              void* d_out, int out_size, void* d_ws, size_t ws_size,
                              hipStream_t stream) {
  const float* q  = (const float*)d_in[0];
  const float* Wq = (const float*)d_in[1];
  const float* bq = (const float*)d_in[2];
  const float* Wk = (const float*)d_in[3];
  const float* bk = (const float*)d_in[4];
  const float* Wv = (const float*)d_in[5];
  const float* bv = (const float*)d_in[6];
  const float* Wo = (const float*)d_in[7];
  const float* bo = (const float*)d_in[8];

  char* ws = (char*)d_ws;
  const size_t MB = 1024 * 1024;
  u16* Xb  = (u16*)(ws + 0);        // 8 MB  [4096][1024] bf16
  u16* WqT = (u16*)(ws + 8 * MB);   // 2 MB  [N][K] bf16
  u16* WkT = (u16*)(ws + 10 * MB);
  u16* WvT = (u16*)(ws + 12 * MB);
  u16* WoT = (u16*)(ws + 14 * MB);
  u16* Qh  = (u16*)(ws + 16 * MB);  // 8 MB  [bh][S][64]
  u16* Kh  = (u16*)(ws + 24 * MB);
  u16* Vh  = (u16*)(ws + 32 * MB);
  u16* Vt  = (u16*)(ws + 40 * MB);  // 8 MB  [bh][64][S]
  u16* Ob  = (u16*)(ws + 48 * MB);  // 8 MB  [B,S,D]

  convert_f2b_kernel<<<4096, 256, 0, stream>>>(q, Xb);
  transpose_w_kernel<<<dim3(16, 16, 4), 256, 0, stream>>>(Wq, Wk, Wv, Wo,
                                                          WqT, WkT, WvT, WoT);
  gemm_qkv_kernel<<<dim3(8, 32, 3), 256, 0, stream>>>(Xb, WqT, WkT, WvT,
                                                      bq, bk, bv, Qh, Kh, Vh);
  transpose_v_kernel<<<dim3(32, 32), 256, 0, stream>>>(Vh, Vt);
  attn_kernel<<<2048, 256, 0, stream>>>(Qh, Kh, Vt, Ob);
  gemm_out_kernel<<<dim3(8, 64), 256, 0, stream>>>(Ob, WoT, bo, (float*)d_out);
}

// Round 13
// 118.501 us; speedup vs baseline: 1.1824x; 1.1824x over previous
//
#include <hip/hip_runtime.h>
#include <hip/hip_bf16.h>

typedef unsigned short u16;
typedef __attribute__((ext_vector_type(8))) __bf16 bf16x8;
typedef __attribute__((ext_vector_type(4))) float f32x4;

#define S_LEN 2048
#define DMODEL 1024
#define NHEAD 16
#define HSZ 64

__device__ __forceinline__ u16 f2bf(float f) {
  union { __hip_bfloat16 b; u16 u; } c;
  c.b = __float2bfloat16(f);
  return c.u;
}

__device__ __forceinline__ float bf2f(u16 u) {
  union { unsigned int i; float f; } c;
  c.i = ((unsigned int)u) << 16;
  return c.f;
}

// raw v_exp_f32 (D = 2^S0)
__device__ __forceinline__ float fexp2(float x) {
#if __has_builtin(__builtin_amdgcn_exp2f)
  return __builtin_amdgcn_exp2f(x);
#else
  return exp2f(x);
#endif
}

// v_cvt_pk_bf16_f32: pack 2 f32 -> 2 bf16 (RNE)
__device__ __forceinline__ unsigned int cvtpk(float lo, float hi) {
  unsigned int r;
  asm("v_cvt_pk_bf16_f32 %0, %1, %2" : "=v"(r) : "v"(lo), "v"(hi));
  return r;
}

__device__ __forceinline__ void gload_lds16(const void* g, void* l) {
  __builtin_amdgcn_global_load_lds(
      (const __attribute__((address_space(1))) void*)g,
      (__attribute__((address_space(3))) void*)l, 16, 0, 0);
}

__device__ __forceinline__ f32x4 mfma16(bf16x8 a, bf16x8 b, f32x4 c) {
  return __builtin_amdgcn_mfma_f32_16x16x32_bf16(a, b, c, 0, 0, 0);
}

// ---------------- fp32 -> bf16 convert (vectorized) ----------------
__global__ __launch_bounds__(256) void convert_f2b_kernel(const float* __restrict__ in,
                                                          u16* __restrict__ out) {
  int i = (blockIdx.x * 256 + threadIdx.x) * 4;
  float4 v = *(const float4*)(in + i);
  ushort4 o;
  o.x = f2bf(v.x); o.y = f2bf(v.y); o.z = f2bf(v.z); o.w = f2bf(v.w);
  *(ushort4*)(out + i) = o;
}

// ------------- W [K][N] fp32 -> W^T [N][K] bf16 (LDS tiled) -------------
__global__ __launch_bounds__(256) void transpose_w_kernel(
    const float* __restrict__ W0, const float* __restrict__ W1,
    const float* __restrict__ W2, const float* __restrict__ W3,
    u16* __restrict__ T0, u16* __restrict__ T1,
    u16* __restrict__ T2, u16* __restrict__ T3) {
  int z = blockIdx.z;
  const float* W = (z == 0) ? W0 : ((z == 1) ? W1 : ((z == 2) ? W2 : W3));
  u16* T = (z == 0) ? T0 : ((z == 1) ? T1 : ((z == 2) ? T2 : T3));
  __shared__ float tile[64][65];
  int t = threadIdx.x;
  int k0 = blockIdx.y * 64, n0 = blockIdx.x * 64;
#pragma unroll
  for (int j = 0; j < 4; ++j) {
    int idx = j * 256 + t;
    int row = idx >> 4, c4 = idx & 15;
    float4 v = *(const float4*)(W + (size_t)(k0 + row) * DMODEL + n0 + c4 * 4);
    tile[row][c4 * 4 + 0] = v.x; tile[row][c4 * 4 + 1] = v.y;
    tile[row][c4 * 4 + 2] = v.z; tile[row][c4 * 4 + 3] = v.w;
  }
  __syncthreads();
#pragma unroll
  for (int j = 0; j < 4; ++j) {
    int idx = j * 256 + t;
    int orow = idx >> 4, c4 = idx & 15;
    ushort4 o;
    o.x = f2bf(tile[c4 * 4 + 0][orow]);
    o.y = f2bf(tile[c4 * 4 + 1][orow]);
    o.z = f2bf(tile[c4 * 4 + 2][orow]);
    o.w = f2bf(tile[c4 * 4 + 3][orow]);
    *(ushort4*)(T + (size_t)(n0 + orow) * DMODEL + k0 + c4 * 4) = o;
  }
}

// ------------- Vh [bh][S][64] -> Vt [bh][64][S] bf16 -------------
__global__ __launch_bounds__(256) void transpose_v_kernel(const u16* __restrict__ Vh,
                                                          u16* __restrict__ Vt) {
  int bh = blockIdx.y;
  int s0 = blockIdx.x * 64;
  __shared__ __align__(16) u16 tile[64][72];
  int t = threadIdx.x;
#pragma unroll
  for (int j = 0; j < 4; ++j) {
    int idx = j * 256 + t;
    int row = idx >> 4, c4 = idx & 15;
    *(ushort4*)&tile[row][c4 * 4] =
        *(const ushort4*)(Vh + ((size_t)bh * S_LEN + s0 + row) * HSZ + c4 * 4);
  }
  __syncthreads();
#pragma unroll
  for (int j = 0; j < 4; ++j) {
    int idx = j * 256 + t;
    int orow = idx >> 4, c4 = idx & 15;
    ushort4 o;
    o.x = tile[c4 * 4 + 0][orow];
    o.y = tile[c4 * 4 + 1][orow];
    o.z = tile[c4 * 4 + 2][orow];
    o.w = tile[c4 * 4 + 3][orow];
    *(ushort4*)(Vt + ((size_t)bh * HSZ + orow) * S_LEN + s0 + c4 * 4) = o;
  }
}

// ------------- GEMM core, templated on m-frags/wave (WM*32 = tile rows) -------------
template <int WM>
__device__ __forceinline__ void gemm_core(const u16* __restrict__ A,
                                          const u16* __restrict__ Bt,
                                          u16* ldsbuf, f32x4 (&acc)[WM][4],
                                          int m0, int n0) {
  const int t = threadIdx.x;
  const int wave = t >> 6, lane = t & 63;
  const int l15 = lane & 15, l4 = lane >> 4;
  const int wr = wave >> 1, wc = wave & 1;
  u16* Asm = ldsbuf;                 // [WM*32][32]
  u16* Bsm = ldsbuf + WM * 1024;     // [128][32]
  for (int kt = 0; kt < DMODEL / 32; ++kt) {
    int kb = kt * 32;
#pragma unroll
    for (int j = 0; j < WM / 2; ++j) {
      int ci = j * 256 + t;
      int row = ci >> 2, kc = ci & 3;
      gload_lds16(A + (size_t)(m0 + row) * DMODEL + kb + kc * 8,
                  Asm + (j * 256 + wave * 64) * 8);
    }
#pragma unroll
    for (int j = 0; j < 2; ++j) {
      int ci = j * 256 + t;
      int row = ci >> 2, kc = ci & 3;
      gload_lds16(Bt + (size_t)(n0 + row) * DMODEL + kb + kc * 8,
                  Bsm + (j * 256 + wave * 64) * 8);
    }
    __syncthreads();
    bf16x8 af[WM], bfr[4];
#pragma unroll
    for (int m = 0; m < WM; ++m)
      af[m] = *(const bf16x8*)(Asm + ((wr * (WM * 16) + m * 16 + l15) * 32 + l4 * 8));
#pragma unroll
    for (int n = 0; n < 4; ++n)
      bfr[n] = *(const bf16x8*)(Bsm + ((wc * 64 + n * 16 + l15) * 32 + l4 * 8));
#pragma unroll
    for (int m = 0; m < WM; ++m)
#pragma unroll
      for (int n = 0; n < 4; ++n)
        acc[m][n] = mfma16(af[m], bfr[n], acc[m][n]);
    __syncthreads();
  }
}

// ------------- QKV projection; Q pre-scaled by 0.125*log2(e) (exp2 domain) -------------
__global__ __launch_bounds__(256) void gemm_qkv_kernel(
    const u16* __restrict__ A, const u16* __restrict__ B0, const u16* __restrict__ B1,
    const u16* __restrict__ B2, const float* __restrict__ bias0,
    const float* __restrict__ bias1, const float* __restrict__ bias2,
    u16* __restrict__ d0, u16* __restrict__ d1, u16* __restrict__ d2) {
  __shared__ __align__(16) u16 lds[8192];
  int z = blockIdx.z;
  const u16* Bt = (z == 0) ? B0 : ((z == 1) ? B1 : B2);
  const float* bias = (z == 0) ? bias0 : ((z == 1) ? bias1 : bias2);
  u16* dst = (z == 0) ? d0 : ((z == 1) ? d1 : d2);
  const float sc = (z == 0) ? 0.18033688011112042f : 1.0f;  // 0.125*log2e
  int m0 = blockIdx.y * 128, n0 = blockIdx.x * 128;
  f32x4 acc[4][4] = {};
  gemm_core<4>(A, Bt, lds, acc, m0, n0);
  const int t = threadIdx.x;
  const int wave = t >> 6, lane = t & 63, l15 = lane & 15, l4 = lane >> 4;
  const int wr = wave >> 1, wc = wave & 1;
#pragma unroll
  for (int n = 0; n < 4; ++n) {
    int colg = n0 + wc * 64 + n * 16 + l15;
    float bn = bias[colg];
    int h = colg >> 6, hs = colg & 63;
#pragma unroll
    for (int m = 0; m < 4; ++m) {
#pragma unroll
      for (int i = 0; i < 4; ++i) {
        int rowg = m0 + wr * 64 + m * 16 + 4 * l4 + i;
        int b = rowg >> 11, s = rowg & 2047;
        dst[(size_t)(b * NHEAD + h) * S_LEN * HSZ + (size_t)s * HSZ + hs] =
            f2bf((acc[m][n][i] + bn) * sc);
      }
    }
  }
}

// ------------- output projection: 64x128 tile, fp32 out -------------
__global__ __launch_bounds__(256) void gemm_out_kernel(const u16* __restrict__ A,
                                                       const u16* __restrict__ Bt,
                                                       const float* __restrict__ bias,
                                                       float* __restrict__ out) {
  __shared__ __align__(16) u16 lds[6144];
  int m0 = blockIdx.y * 64, n0 = blockIdx.x * 128;
  f32x4 acc[2][4] = {};
  gemm_core<2>(A, Bt, lds, acc, m0, n0);
  const int t = threadIdx.x;
  const int wave = t >> 6, lane = t & 63, l15 = lane & 15, l4 = lane >> 4;
  const int wr = wave >> 1, wc = wave & 1;
#pragma unroll
  for (int n = 0; n < 4; ++n) {
    int colg = n0 + wc * 64 + n * 16 + l15;
    float bn = bias[colg];
#pragma unroll
    for (int m = 0; m < 2; ++m) {
#pragma unroll
      for (int i = 0; i < 4; ++i) {
        int rowg = m0 + wr * 32 + m * 16 + 4 * l4 + i;
        out[(size_t)rowg * DMODEL + colg] = acc[m][n][i] + bn;
      }
    }
  }
}

// ------------- flash attention (causal), LDS-shared K/V, single-buffer -------------
// Block = 128 q-rows (4 waves x 32 rows, each wave owns its rows; no merge).
// Block walks kv ONCE; each 64-wide K/V tile staged to LDS and consumed by
// all 4 waves -> K/V traffic / 4. Correct-by-construction sync:
//   barrier A (readers of t-1 done) -> ds_write tile t -> barrier B -> compute.
// Register prefetch of tile t+1 issued after barrier B (hides under compute).
// Compute is UNCONDITIONAL: fully-masked tiles are numerically inert
// (all -1e30 -> exp2 -> 0, corr = 1). Pairing {pk,15-pk}: 36 trips/block
// uniform. Grid 256. Softmax: swapped QK^T, exp2 domain, cvt_pk (R10 lineage).
__global__ __launch_bounds__(256, 2) void attn_kernel(const u16* __restrict__ Qh,
                                                      const u16* __restrict__ Kh,
                                                      const u16* __restrict__ Vt,
                                                      u16* __restrict__ Ob) {
  __shared__ __align__(16) u16 Ksm[64][72];  // [kv][hs]
  __shared__ __align__(16) u16 Vsm[64][72];  // [hs][kv]
  __shared__ __align__(16) u16 Pl[4][32][72];
  const int tixd = threadIdx.x;
  const int wave = tixd >> 6, lane = tixd & 63;
  const int l15 = lane & 15, l4 = lane >> 4;
  const int id = blockIdx.x;
  const int bh = (id & 7) * 4 + ((id >> 3) & 3);  // XCD-local heads
  const int pk = id >> 5;                         // pair index 0..7
  const u16* Qb = Qh + (size_t)bh * S_LEN * HSZ;
  const u16* Kb = Kh + (size_t)bh * S_LEN * HSZ;
  const u16* Vb = Vt + (size_t)bh * HSZ * S_LEN;
  const int shbase = l4 * 20;
  u16 (*P)[72] = Pl[wave];
  const int b = bh >> 4, h = bh & 15;
  // staging: thread -> row sr in [0,64), col base scb in {0,16,32,48}
  const int sr = tixd >> 2;
  const int scb = (tixd & 3) * 16;

#pragma unroll 1
  for (int ph = 0; ph < 2; ++ph) {
    const int pp = ph ? (15 - pk) : pk;
    const int q0 = pp * 128 + wave * 32;  // this wave's rows
    const int nt = 2 * pp + 2;            // staged kv tiles of 64

    bf16x8 qf[2][2];
#pragma unroll
    for (int m = 0; m < 2; ++m)
#pragma unroll
      for (int kc = 0; kc < 2; ++kc)
        qf[m][kc] = *(const bf16x8*)(Qb + (size_t)(q0 + m * 16 + l15) * HSZ + kc * 32 + l4 * 8);

    f32x4 oacc[2][4] = {};
    float mrun[2] = {-1e30f, -1e30f};
    float lrun[2] = {0.f, 0.f};

    // prologue: tile 0 into regs
    uint4 ka0 = *(const uint4*)(Kb + (size_t)sr * HSZ + scb);
    uint4 ka1 = *(const uint4*)(Kb + (size_t)sr * HSZ + scb + 8);
    uint4 va0 = *(const uint4*)(Vb + (size_t)sr * S_LEN + scb);
    uint4 va1 = *(const uint4*)(Vb + (size_t)sr * S_LEN + scb + 8);

#pragma unroll 1
    for (int t = 0; t < nt; ++t) {
      __syncthreads();  // A: all waves' reads of tile t-1 complete
      *(uint4*)&Ksm[sr][scb]     = ka0;
      *(uint4*)&Ksm[sr][scb + 8] = ka1;
      *(uint4*)&Vsm[sr][scb]     = va0;
      *(uint4*)&Vsm[sr][scb + 8] = va1;
      __syncthreads();  // B: tile t visible to all
      if (t + 1 < nt) {  // prefetch tile t+1; latency hides under compute
        const int kvn = (t + 1) * 64;
        ka0 = *(const uint4*)(Kb + (size_t)(kvn + sr) * HSZ + scb);
        ka1 = *(const uint4*)(Kb + (size_t)(kvn + sr) * HSZ + scb + 8);
        va0 = *(const uint4*)(Vb + (size_t)sr * S_LEN + kvn + scb);
        va1 = *(const uint4*)(Vb + (size_t)sr * S_LEN + kvn + scb + 8);
      }
      const int kv0 = t * 64;

      bf16x8 kf[4][2];
#pragma unroll
      for (int n = 0; n < 4; ++n)
#pragma unroll
        for (int kc = 0; kc < 2; ++kc)
          kf[n][kc] = *(const bf16x8*)&Ksm[n * 16 + l15][kc * 32 + l4 * 8];

      f32x4 sacc[2][4] = {};
#pragma unroll
      for (int m = 0; m < 2; ++m)
#pragma unroll
        for (int n = 0; n < 4; ++n) {
          sacc[m][n] = mfma16(kf[n][0], qf[m][0], sacc[m][n]);
          sacc[m][n] = mfma16(kf[n][1], qf[m][1], sacc[m][n]);
        }

      bf16x8 vf[2][4];
#pragma unroll
      for (int kb = 0; kb < 2; ++kb)
#pragma unroll
        for (int n = 0; n < 4; ++n)
          vf[kb][n] = *(const bf16x8*)&Vsm[n * 16 + l15][kb * 32 + l4 * 8];

      if (kv0 + 63 > q0) {
#pragma unroll
        for (int m = 0; m < 2; ++m)
#pragma unroll
          for (int n = 0; n < 4; ++n)
#pragma unroll
            for (int i = 0; i < 4; ++i)
              if (kv0 + n * 16 + 4 * l4 + i > q0 + m * 16 + l15) sacc[m][n][i] = -1e30f;
      }

#pragma unroll
      for (int m = 0; m < 2; ++m) {
        float a0 = fmaxf(fmaxf(sacc[m][0][0], sacc[m][0][1]),
                         fmaxf(sacc[m][0][2], sacc[m][0][3]));
        float a1 = fmaxf(fmaxf(sacc[m][1][0], sacc[m][1][1]),
                         fmaxf(sacc[m][1][2], sacc[m][1][3]));
        float a2 = fmaxf(fmaxf(sacc[m][2][0], sacc[m][2][1]),
                         fmaxf(sacc[m][2][2], sacc[m][2][3]));
        float a3 = fmaxf(fmaxf(sacc[m][3][0], sacc[m][3][1]),
                         fmaxf(sacc[m][3][2], sacc[m][3][3]));
        float tm = fmaxf(fmaxf(a0, a1), fmaxf(a2, a3));
        tm = fmaxf(tm, __shfl_xor(tm, 16));
        tm = fmaxf(tm, __shfl_xor(tm, 32));
        float mnew = fmaxf(mrun[m], tm);
        float corr = fexp2(mrun[m] - mnew);
        mrun[m] = mnew;
        float rs = 0.f;
#pragma unroll
        for (int n = 0; n < 4; ++n)
#pragma unroll
          for (int i = 0; i < 4; ++i) {
            float pv = fexp2(sacc[m][n][i] - mnew);
            sacc[m][n][i] = pv;
            rs += pv;
          }
        rs += __shfl_xor(rs, 16);
        rs += __shfl_xor(rs, 32);
        lrun[m] = lrun[m] * corr + rs;
        float cc0 = __shfl(corr, shbase + 0);
        float cc1 = __shfl(corr, shbase + 1);
        float cc2 = __shfl(corr, shbase + 2);
        float cc3 = __shfl(corr, shbase + 3);
#pragma unroll
        for (int n = 0; n < 4; ++n) {
          oacc[m][n][0] *= cc0; oacc[m][n][1] *= cc1;
          oacc[m][n][2] *= cc2; oacc[m][n][3] *= cc3;
        }
#pragma unroll
        for (int n = 0; n < 4; ++n) {
          uint2 pkk;
          pkk.x = cvtpk(sacc[m][n][0], sacc[m][n][1]);
          pkk.y = cvtpk(sacc[m][n][2], sacc[m][n][3]);
          *(uint2*)&P[m * 16 + l15][n * 16 + 4 * l4] = pkk;
        }
      }

#pragma unroll
      for (int kb = 0; kb < 2; ++kb) {
        bf16x8 pf0 = *(const bf16x8*)&P[l15][kb * 32 + l4 * 8];
        bf16x8 pf1 = *(const bf16x8*)&P[16 + l15][kb * 32 + l4 * 8];
#pragma unroll
        for (int n = 0; n < 4; ++n) {
          oacc[0][n] = mfma16(pf0, vf[kb][n], oacc[0][n]);
          oacc[1][n] = mfma16(pf1, vf[kb][n], oacc[1][n]);
        }
      }
    }

    // finalize this wave's 32 rows directly (no cross-wave merge)
#pragma unroll
    for (int m = 0; m < 2; ++m) {
      float invm = 1.0f / lrun[m];
#pragma unroll
      for (int i = 0; i < 4; ++i) {
        float iv = __shfl(invm, shbase + i);
        int srow = q0 + m * 16 + 4 * l4 + i;
#pragma unroll
        for (int n = 0; n < 4; ++n) {
          int d = h * HSZ + n * 16 + l15;
          Ob[((size_t)b * S_LEN + srow) * DMODEL + d] = f2bf(oacc[m][n][i] * iv);
        }
      }
    }
  }
}

extern "C" void kernel_launch(void* const* d_in, const int* in_sizes, int n_in,
                              void* d_out, int out_size, void* d_ws, size_t ws_size,
                              hipStream_t stream) {
  const float* q  = (const float*)d_in[0];
  const float* Wq = (const float*)d_in[1];
  const float* bq = (const float*)d_in[2];
  const float* Wk = (const float*)d_in[3];
  const float* bk = (const float*)d_in[4];
  const float* Wv = (const float*)d_in[5];
  const float* bv = (const float*)d_in[6];
  const float* Wo = (const float*)d_in[7];
  const float* bo = (const float*)d_in[8];

  char* ws = (char*)d_ws;
  const size_t MB = 1024 * 1024;
  u16* Xb  = (u16*)(ws + 0);        // 8 MB  [4096][1024] bf16
  u16* WqT = (u16*)(ws + 8 * MB);   // 2 MB  [N][K] bf16
  u16* WkT = (u16*)(ws + 10 * MB);
  u16* WvT = (u16*)(ws + 12 * MB);
  u16* WoT = (u16*)(ws + 14 * MB);
  u16* Qh  = (u16*)(ws + 16 * MB);  // 8 MB  [bh][S][64]
  u16* Kh  = (u16*)(ws + 24 * MB);
  u16* Vh  = (u16*)(ws + 32 * MB);
  u16* Vt  = (u16*)(ws + 40 * MB);  // 8 MB  [bh][64][S]
  u16* Ob  = (u16*)(ws + 48 * MB);  // 8 MB  [B,S,D]

  convert_f2b_kernel<<<4096, 256, 0, stream>>>(q, Xb);
  transpose_w_kernel<<<dim3(16, 16, 4), 256, 0, stream>>>(Wq, Wk, Wv, Wo,
                                                          WqT, WkT, WvT, WoT);
  gemm_qkv_kernel<<<dim3(8, 32, 3), 256, 0, stream>>>(Xb, WqT, WkT, WvT,
                                                      bq, bk, bv, Qh, Kh, Vh);
  transpose_v_kernel<<<dim3(32, 32), 256, 0, stream>>>(Vh, Vt);
  attn_kernel<<<256, 256, 0, stream>>>(Qh, Kh, Vt, Ob);
  gemm_out_kernel<<<dim3(8, 64), 256, 0, stream>>>(Ob, WoT, bo, (float*)d_out);
}

// Round 14
// 115.909 us; speedup vs baseline: 1.2088x; 1.0224x over previous
//
#include <hip/hip_runtime.h>
#include <hip/hip_bf16.h>

typedef unsigned short u16;
typedef __attribute__((ext_vector_type(8))) __bf16 bf16x8;
typedef __attribute__((ext_vector_type(4))) float f32x4;

#define S_LEN 2048
#define DMODEL 1024
#define NHEAD 16
#define HSZ 64

__device__ __forceinline__ u16 f2bf(float f) {
  union { __hip_bfloat16 b; u16 u; } c;
  c.b = __float2bfloat16(f);
  return c.u;
}

__device__ __forceinline__ float bf2f(u16 u) {
  union { unsigned int i; float f; } c;
  c.i = ((unsigned int)u) << 16;
  return c.f;
}

// raw v_exp_f32 (D = 2^S0)
__device__ __forceinline__ float fexp2(float x) {
#if __has_builtin(__builtin_amdgcn_exp2f)
  return __builtin_amdgcn_exp2f(x);
#else
  return exp2f(x);
#endif
}

// v_cvt_pk_bf16_f32: pack 2 f32 -> 2 bf16 (RNE)
__device__ __forceinline__ unsigned int cvtpk(float lo, float hi) {
  unsigned int r;
  asm("v_cvt_pk_bf16_f32 %0, %1, %2" : "=v"(r) : "v"(lo), "v"(hi));
  return r;
}

__device__ __forceinline__ void gload_lds16(const void* g, void* l) {
  __builtin_amdgcn_global_load_lds(
      (const __attribute__((address_space(1))) void*)g,
      (__attribute__((address_space(3))) void*)l, 16, 0, 0);
}

__device__ __forceinline__ f32x4 mfma16(bf16x8 a, bf16x8 b, f32x4 c) {
  return __builtin_amdgcn_mfma_f32_16x16x32_bf16(a, b, c, 0, 0, 0);
}

// ---------------- fp32 -> bf16 convert (vectorized) ----------------
__global__ __launch_bounds__(256) void convert_f2b_kernel(const float* __restrict__ in,
                                                          u16* __restrict__ out) {
  int i = (blockIdx.x * 256 + threadIdx.x) * 4;
  float4 v = *(const float4*)(in + i);
  ushort4 o;
  o.x = f2bf(v.x); o.y = f2bf(v.y); o.z = f2bf(v.z); o.w = f2bf(v.w);
  *(ushort4*)(out + i) = o;
}

// ------------- W [K][N] fp32 -> W^T [N][K] bf16 (LDS tiled) -------------
__global__ __launch_bounds__(256) void transpose_w_kernel(
    const float* __restrict__ W0, const float* __restrict__ W1,
    const float* __restrict__ W2, const float* __restrict__ W3,
    u16* __restrict__ T0, u16* __restrict__ T1,
    u16* __restrict__ T2, u16* __restrict__ T3) {
  int z = blockIdx.z;
  const float* W = (z == 0) ? W0 : ((z == 1) ? W1 : ((z == 2) ? W2 : W3));
  u16* T = (z == 0) ? T0 : ((z == 1) ? T1 : ((z == 2) ? T2 : T3));
  __shared__ float tile[64][65];
  int t = threadIdx.x;
  int k0 = blockIdx.y * 64, n0 = blockIdx.x * 64;
#pragma unroll
  for (int j = 0; j < 4; ++j) {
    int idx = j * 256 + t;
    int row = idx >> 4, c4 = idx & 15;
    float4 v = *(const float4*)(W + (size_t)(k0 + row) * DMODEL + n0 + c4 * 4);
    tile[row][c4 * 4 + 0] = v.x; tile[row][c4 * 4 + 1] = v.y;
    tile[row][c4 * 4 + 2] = v.z; tile[row][c4 * 4 + 3] = v.w;
  }
  __syncthreads();
#pragma unroll
  for (int j = 0; j < 4; ++j) {
    int idx = j * 256 + t;
    int orow = idx >> 4, c4 = idx & 15;
    ushort4 o;
    o.x = f2bf(tile[c4 * 4 + 0][orow]);
    o.y = f2bf(tile[c4 * 4 + 1][orow]);
    o.z = f2bf(tile[c4 * 4 + 2][orow]);
    o.w = f2bf(tile[c4 * 4 + 3][orow]);
    *(ushort4*)(T + (size_t)(n0 + orow) * DMODEL + k0 + c4 * 4) = o;
  }
}

// ------------- Vh [bh][S][64] -> Vt [bh][64][S] bf16 -------------
__global__ __launch_bounds__(256) void transpose_v_kernel(const u16* __restrict__ Vh,
                                                          u16* __restrict__ Vt) {
  int bh = blockIdx.y;
  int s0 = blockIdx.x * 64;
  __shared__ __align__(16) u16 tile[64][72];
  int t = threadIdx.x;
#pragma unroll
  for (int j = 0; j < 4; ++j) {
    int idx = j * 256 + t;
    int row = idx >> 4, c4 = idx & 15;
    *(ushort4*)&tile[row][c4 * 4] =
        *(const ushort4*)(Vh + ((size_t)bh * S_LEN + s0 + row) * HSZ + c4 * 4);
  }
  __syncthreads();
#pragma unroll
  for (int j = 0; j < 4; ++j) {
    int idx = j * 256 + t;
    int orow = idx >> 4, c4 = idx & 15;
    ushort4 o;
    o.x = tile[c4 * 4 + 0][orow];
    o.y = tile[c4 * 4 + 1][orow];
    o.z = tile[c4 * 4 + 2][orow];
    o.w = tile[c4 * 4 + 3][orow];
    *(ushort4*)(Vt + ((size_t)bh * HSZ + orow) * S_LEN + s0 + c4 * 4) = o;
  }
}

// ------------- GEMM core, templated on m-frags/wave (WM*32 = tile rows) -------------
template <int WM>
__device__ __forceinline__ void gemm_core(const u16* __restrict__ A,
                                          const u16* __restrict__ Bt,
                                          u16* ldsbuf, f32x4 (&acc)[WM][4],
                                          int m0, int n0) {
  const int t = threadIdx.x;
  const int wave = t >> 6, lane = t & 63;
  const int l15 = lane & 15, l4 = lane >> 4;
  const int wr = wave >> 1, wc = wave & 1;
  u16* Asm = ldsbuf;                 // [WM*32][32]
  u16* Bsm = ldsbuf + WM * 1024;     // [128][32]
  for (int kt = 0; kt < DMODEL / 32; ++kt) {
    int kb = kt * 32;
#pragma unroll
    for (int j = 0; j < WM / 2; ++j) {
      int ci = j * 256 + t;
      int row = ci >> 2, kc = ci & 3;
      gload_lds16(A + (size_t)(m0 + row) * DMODEL + kb + kc * 8,
                  Asm + (j * 256 + wave * 64) * 8);
    }
#pragma unroll
    for (int j = 0; j < 2; ++j) {
      int ci = j * 256 + t;
      int row = ci >> 2, kc = ci & 3;
      gload_lds16(Bt + (size_t)(n0 + row) * DMODEL + kb + kc * 8,
                  Bsm + (j * 256 + wave * 64) * 8);
    }
    __syncthreads();
    bf16x8 af[WM], bfr[4];
#pragma unroll
    for (int m = 0; m < WM; ++m)
      af[m] = *(const bf16x8*)(Asm + ((wr * (WM * 16) + m * 16 + l15) * 32 + l4 * 8));
#pragma unroll
    for (int n = 0; n < 4; ++n)
      bfr[n] = *(const bf16x8*)(Bsm + ((wc * 64 + n * 16 + l15) * 32 + l4 * 8));
#pragma unroll
    for (int m = 0; m < WM; ++m)
#pragma unroll
      for (int n = 0; n < 4; ++n)
        acc[m][n] = mfma16(af[m], bfr[n], acc[m][n]);
    __syncthreads();
  }
}

// ------------- QKV projection; Q pre-scaled by 0.125*log2(e) (exp2 domain) -------------
__global__ __launch_bounds__(256) void gemm_qkv_kernel(
    const u16* __restrict__ A, const u16* __restrict__ B0, const u16* __restrict__ B1,
    const u16* __restrict__ B2, const float* __restrict__ bias0,
    const float* __restrict__ bias1, const float* __restrict__ bias2,
    u16* __restrict__ d0, u16* __restrict__ d1, u16* __restrict__ d2) {
  __shared__ __align__(16) u16 lds[8192];
  int z = blockIdx.z;
  const u16* Bt = (z == 0) ? B0 : ((z == 1) ? B1 : B2);
  const float* bias = (z == 0) ? bias0 : ((z == 1) ? bias1 : bias2);
  u16* dst = (z == 0) ? d0 : ((z == 1) ? d1 : d2);
  const float sc = (z == 0) ? 0.18033688011112042f : 1.0f;  // 0.125*log2e
  int m0 = blockIdx.y * 128, n0 = blockIdx.x * 128;
  f32x4 acc[4][4] = {};
  gemm_core<4>(A, Bt, lds, acc, m0, n0);
  const int t = threadIdx.x;
  const int wave = t >> 6, lane = t & 63, l15 = lane & 15, l4 = lane >> 4;
  const int wr = wave >> 1, wc = wave & 1;
#pragma unroll
  for (int n = 0; n < 4; ++n) {
    int colg = n0 + wc * 64 + n * 16 + l15;
    float bn = bias[colg];
    int h = colg >> 6, hs = colg & 63;
#pragma unroll
    for (int m = 0; m < 4; ++m) {
#pragma unroll
      for (int i = 0; i < 4; ++i) {
        int rowg = m0 + wr * 64 + m * 16 + 4 * l4 + i;
        int b = rowg >> 11, s = rowg & 2047;
        dst[(size_t)(b * NHEAD + h) * S_LEN * HSZ + (size_t)s * HSZ + hs] =
            f2bf((acc[m][n][i] + bn) * sc);
      }
    }
  }
}

// ------------- output projection: 64x128 tile, fp32 out -------------
__global__ __launch_bounds__(256) void gemm_out_kernel(const u16* __restrict__ A,
                                                       const u16* __restrict__ Bt,
                                                       const float* __restrict__ bias,
                                                       float* __restrict__ out) {
  __shared__ __align__(16) u16 lds[6144];
  int m0 = blockIdx.y * 64, n0 = blockIdx.x * 128;
  f32x4 acc[2][4] = {};
  gemm_core<2>(A, Bt, lds, acc, m0, n0);
  const int t = threadIdx.x;
  const int wave = t >> 6, lane = t & 63, l15 = lane & 15, l4 = lane >> 4;
  const int wr = wave >> 1, wc = wave & 1;
#pragma unroll
  for (int n = 0; n < 4; ++n) {
    int colg = n0 + wc * 64 + n * 16 + l15;
    float bn = bias[colg];
#pragma unroll
    for (int m = 0; m < 2; ++m) {
#pragma unroll
      for (int i = 0; i < 4; ++i) {
        int rowg = m0 + wr * 32 + m * 16 + 4 * l4 + i;
        out[(size_t)rowg * DMODEL + colg] = acc[m][n][i] + bn;
      }
    }
  }
}

// ------------- flash attention (causal), LDS-shared K/V, 8 waves x 16 rows -------------
// R13 structure (53.5us) with the 128-row block split over 8 waves of 16 rows
// instead of 4 of 32 -> 2 waves/SIMD (was 1): every stall now has a second
// wave to hide under. K/V staging identical (single buffer, two barriers,
// register prefetch of tile t+1 under compute; traffic 147MB). Pairing
// {pk,15-pk}: 36 uniform trips. Grid 256 = 1 block/CU = 8 waves/CU.
// Softmax: swapped QK^T, exp2 domain, raw v_exp, cvt_pk pack.
__global__ __launch_bounds__(512, 2) void attn_kernel(const u16* __restrict__ Qh,
                                                      const u16* __restrict__ Kh,
                                                      const u16* __restrict__ Vt,
                                                      u16* __restrict__ Ob) {
  __shared__ __align__(16) u16 Ksm[64][72];     // [kv][hs]
  __shared__ __align__(16) u16 Vsm[64][72];     // [hs][kv]
  __shared__ __align__(16) u16 Pl[8][16][72];   // per-wave P
  const int tixd = threadIdx.x;
  const int wave = tixd >> 6, lane = tixd & 63;
  const int l15 = lane & 15, l4 = lane >> 4;
  const int id = blockIdx.x;
  const int bh = (id & 7) * 4 + ((id >> 3) & 3);  // XCD-local heads
  const int pk = id >> 5;                         // pair index 0..7
  const u16* Qb = Qh + (size_t)bh * S_LEN * HSZ;
  const u16* Kb = Kh + (size_t)bh * S_LEN * HSZ;
  const u16* Vb = Vt + (size_t)bh * HSZ * S_LEN;
  const int shbase = l4 * 20;
  u16 (*P)[72] = Pl[wave];
  const int b = bh >> 4, h = bh & 15;
  // staging: 512 threads -> row sr in [0,64), col base sc (one uint4 each)
  const int sr = tixd >> 3;
  const int sc = (tixd & 7) * 8;

#pragma unroll 1
  for (int ph = 0; ph < 2; ++ph) {
    const int pp = ph ? (15 - pk) : pk;
    const int q0 = pp * 128 + wave * 16;  // this wave's 16 rows
    const int nt = 2 * pp + 2;            // staged kv tiles of 64

    bf16x8 qf[2];
#pragma unroll
    for (int kc = 0; kc < 2; ++kc)
      qf[kc] = *(const bf16x8*)(Qb + (size_t)(q0 + l15) * HSZ + kc * 32 + l4 * 8);

    f32x4 oacc[4] = {};
    float mrun = -1e30f;
    float lrun = 0.f;

    // prologue: tile 0 into regs
    uint4 ka = *(const uint4*)(Kb + (size_t)sr * HSZ + sc);
    uint4 va = *(const uint4*)(Vb + (size_t)sr * S_LEN + sc);

#pragma unroll 1
    for (int t = 0; t < nt; ++t) {
      __syncthreads();  // A: all waves' reads of tile t-1 complete
      *(uint4*)&Ksm[sr][sc] = ka;
      *(uint4*)&Vsm[sr][sc] = va;
      __syncthreads();  // B: tile t visible to all
      if (t + 1 < nt) {  // prefetch tile t+1; latency hides under compute
        const int kvn = (t + 1) * 64;
        ka = *(const uint4*)(Kb + (size_t)(kvn + sr) * HSZ + sc);
        va = *(const uint4*)(Vb + (size_t)sr * S_LEN + kvn + sc);
      }
      const int kv0 = t * 64;

      bf16x8 kf[4][2];
#pragma unroll
      for (int n = 0; n < 4; ++n)
#pragma unroll
        for (int kc = 0; kc < 2; ++kc)
          kf[n][kc] = *(const bf16x8*)&Ksm[n * 16 + l15][kc * 32 + l4 * 8];

      f32x4 sacc[4] = {};
#pragma unroll
      for (int n = 0; n < 4; ++n) {
        sacc[n] = mfma16(kf[n][0], qf[0], sacc[n]);
        sacc[n] = mfma16(kf[n][1], qf[1], sacc[n]);
      }

      bf16x8 vf[2][4];
#pragma unroll
      for (int kb = 0; kb < 2; ++kb)
#pragma unroll
        for (int n = 0; n < 4; ++n)
          vf[kb][n] = *(const bf16x8*)&Vsm[n * 16 + l15][kb * 32 + l4 * 8];

      if (kv0 + 63 > q0) {
#pragma unroll
        for (int n = 0; n < 4; ++n)
#pragma unroll
          for (int i = 0; i < 4; ++i)
            if (kv0 + n * 16 + 4 * l4 + i > q0 + l15) sacc[n][i] = -1e30f;
      }

      {
        float a0 = fmaxf(fmaxf(sacc[0][0], sacc[0][1]),
                         fmaxf(sacc[0][2], sacc[0][3]));
        float a1 = fmaxf(fmaxf(sacc[1][0], sacc[1][1]),
                         fmaxf(sacc[1][2], sacc[1][3]));
        float a2 = fmaxf(fmaxf(sacc[2][0], sacc[2][1]),
                         fmaxf(sacc[2][2], sacc[2][3]));
        float a3 = fmaxf(fmaxf(sacc[3][0], sacc[3][1]),
                         fmaxf(sacc[3][2], sacc[3][3]));
        float tm = fmaxf(fmaxf(a0, a1), fmaxf(a2, a3));
        tm = fmaxf(tm, __shfl_xor(tm, 16));
        tm = fmaxf(tm, __shfl_xor(tm, 32));
        float mnew = fmaxf(mrun, tm);
        float corr = fexp2(mrun - mnew);
        mrun = mnew;
        float rs = 0.f;
#pragma unroll
        for (int n = 0; n < 4; ++n)
#pragma unroll
          for (int i = 0; i < 4; ++i) {
            float pv = fexp2(sacc[n][i] - mnew);
            sacc[n][i] = pv;
            rs += pv;
          }
        rs += __shfl_xor(rs, 16);
        rs += __shfl_xor(rs, 32);
        lrun = lrun * corr + rs;
        float cc0 = __shfl(corr, shbase + 0);
        float cc1 = __shfl(corr, shbase + 1);
        float cc2 = __shfl(corr, shbase + 2);
        float cc3 = __shfl(corr, shbase + 3);
#pragma unroll
        for (int n = 0; n < 4; ++n) {
          oacc[n][0] *= cc0; oacc[n][1] *= cc1;
          oacc[n][2] *= cc2; oacc[n][3] *= cc3;
        }
#pragma unroll
        for (int n = 0; n < 4; ++n) {
          uint2 pkk;
          pkk.x = cvtpk(sacc[n][0], sacc[n][1]);
          pkk.y = cvtpk(sacc[n][2], sacc[n][3]);
          *(uint2*)&P[l15][n * 16 + 4 * l4] = pkk;
        }
      }

#pragma unroll
      for (int kb = 0; kb < 2; ++kb) {
        bf16x8 pf = *(const bf16x8*)&P[l15][kb * 32 + l4 * 8];
#pragma unroll
        for (int n = 0; n < 4; ++n)
          oacc[n] = mfma16(pf, vf[kb][n], oacc[n]);
      }
    }

    // finalize this wave's 16 rows directly
    {
      float invm = 1.0f / lrun;
#pragma unroll
      for (int i = 0; i < 4; ++i) {
        float iv = __shfl(invm, shbase + i);
        int srow = q0 + 4 * l4 + i;
#pragma unroll
        for (int n = 0; n < 4; ++n) {
          int d = h * HSZ + n * 16 + l15;
          Ob[((size_t)b * S_LEN + srow) * DMODEL + d] = f2bf(oacc[n][i] * iv);
        }
      }
    }
  }
}

extern "C" void kernel_launch(void* const* d_in, const int* in_sizes, int n_in,
                              void* d_out, int out_size, void* d_ws, size_t ws_size,
                              hipStream_t stream) {
  const float* q  = (const float*)d_in[0];
  const float* Wq = (const float*)d_in[1];
  const float* bq = (const float*)d_in[2];
  const float* Wk = (const float*)d_in[3];
  const float* bk = (const float*)d_in[4];
  const float* Wv = (const float*)d_in[5];
  const float* bv = (const float*)d_in[6];
  const float* Wo = (const float*)d_in[7];
  const float* bo = (const float*)d_in[8];

  char* ws = (char*)d_ws;
  const size_t MB = 1024 * 1024;
  u16* Xb  = (u16*)(ws + 0);        // 8 MB  [4096][1024] bf16
  u16* WqT = (u16*)(ws + 8 * MB);   // 2 MB  [N][K] bf16
  u16* WkT = (u16*)(ws + 10 * MB);
  u16* WvT = (u16*)(ws + 12 * MB);
  u16* WoT = (u16*)(ws + 14 * MB);
  u16* Qh  = (u16*)(ws + 16 * MB);  // 8 MB  [bh][S][64]
  u16* Kh  = (u16*)(ws + 24 * MB);
  u16* Vh  = (u16*)(ws + 32 * MB);
  u16* Vt  = (u16*)(ws + 40 * MB);  // 8 MB  [bh][64][S]
  u16* Ob  = (u16*)(ws + 48 * MB);  // 8 MB  [B,S,D]

  convert_f2b_kernel<<<4096, 256, 0, stream>>>(q, Xb);
  transpose_w_kernel<<<dim3(16, 16, 4), 256, 0, stream>>>(Wq, Wk, Wv, Wo,
                                                          WqT, WkT, WvT, WoT);
  gemm_qkv_kernel<<<dim3(8, 32, 3), 256, 0, stream>>>(Xb, WqT, WkT, WvT,
                                                      bq, bk, bv, Qh, Kh, Vh);
  transpose_v_kernel<<<dim3(32, 32), 256, 0, stream>>>(Vh, Vt);
  attn_kernel<<<256, 512, 0, stream>>>(Qh, Kh, Vt, Ob);
  gemm_out_kernel<<<dim3(8, 64), 256, 0, stream>>>(Ob, WoT, bo, (float*)d_out);
}